// Round 3
// baseline (868.107 us; speedup 1.0000x reference)
//
#include <hip/hip_runtime.h>
#include <math.h>

// Sizes (fixed by the problem)
#define B_  64
#define L_  48
#define E_  300
#define F0_ 300
#define NEGP (-1e30f)
#define XROW 320      // X / whT row stride in halves (640B, 16B aligned)

typedef __attribute__((ext_vector_type(8))) _Float16 half8;
typedef __attribute__((ext_vector_type(8))) short   short8;
typedef __attribute__((ext_vector_type(4))) float   float4v;

// -------- workspace layout (float offsets) --------
// r1    : 0        .. 921600      (B*L*E) fp32
// r2    : 921600   .. 1843200
// s1p   : 1843200  .. 4608000     (B*3*48*300) pre-tanh partial max over j per j-tile
//   X   : 1843200  .. 2826240     [pre-k2 alias] 6144x320 fp16 gathered embeddings
//   whT : 2826240  .. 2972160     [pre-k2 alias] 3x304x320 fp16 conv weights
// s2p   : 4608000  .. 7372800
// s1    : 7372800  .. 8294400
// s2    : 8294400  .. 9216000
// h1    : 9216000  .. 9235200
// h2    : 9235200  .. 9254400
// Bprep : 9254400  .. 9351680     95x256x8 fp16 pre-packed fc0_w chunks

// ---------------- prep kernels ----------------

// whT[k][o][kk] = conv_w[(o*300+kk)*3+k]  (o<300, kk<300 else 0)
__global__ void kp_w(const float* __restrict__ conv_w, _Float16* __restrict__ whT) {
    int idx = blockIdx.x * 256 + threadIdx.x;
    if (idx >= 3 * 304 * XROW) return;
    int k = idx / (304 * XROW);
    int rest = idx - k * 304 * XROW;
    int o = rest / XROW;
    int kk = rest - o * XROW;
    float v = 0.f;
    if (o < 300 && kk < 300) v = conv_w[(o * 300 + kk) * 3 + k];
    whT[idx] = (_Float16)v;
}

// Bprep[m][tid][e]: the exact half8 thread `tid` stages to Bt for chunk m of k2.
// m = nc*19+kc ; f = nc*64 + tid/4 ; k = kc*32 + (tid%4)*8 + e
// K axis: [0,300)=d-part, [304,604)=p-part (e=k-304), else 0.
__global__ void kp_b(const float* __restrict__ fc0w, _Float16* __restrict__ Bprep) {
    int m = blockIdx.x;
    int tid = threadIdx.x;
    int nc = m / 19, kc = m - nc * 19;
    int f = nc * 64 + (tid >> 2);
    int kbase = kc * 32 + (tid & 3) * 8;
    half8 hv;
#pragma unroll
    for (int e = 0; e < 8; ++e) {
        int k = kbase + e;
        float v = 0.f;
        if (f < 300) {
            if (k < 300) v = fc0w[f * 600 + k];
            else if (k >= 304 && k < 604) v = fc0w[f * 600 + k - 4];
        }
        hv[e] = (_Float16)v;
    }
    *reinterpret_cast<half8*>(Bprep + ((long)m * 256 + tid) * 8) = hv;
}

// X[(s,b,l)][i] = fp16(emb[q_s[b,l], i])  (i<300 else 0); row stride XROW
__global__ void kp_x(const int* __restrict__ q1, const int* __restrict__ q2,
                     const float* __restrict__ emb, _Float16* __restrict__ X) {
    int u = blockIdx.x * 256 + threadIdx.x;   // half8 index
    if (u >= 6144 * (XROW / 8)) return;
    int g = u / (XROW / 8);
    int e8 = (u - g * (XROW / 8)) * 8;
    int s = g / 3072;
    int rem = g - s * 3072;                   // b*48+l
    long row = (long)((s ? q2 : q1)[rem]) * 300;
    half8 hv;
    if (e8 + 7 < 300) {
        float4 a = *reinterpret_cast<const float4*>(emb + row + e8);
        float4 c = *reinterpret_cast<const float4*>(emb + row + e8 + 4);
        hv[0] = (_Float16)a.x; hv[1] = (_Float16)a.y; hv[2] = (_Float16)a.z; hv[3] = (_Float16)a.w;
        hv[4] = (_Float16)c.x; hv[5] = (_Float16)c.y; hv[6] = (_Float16)c.z; hv[7] = (_Float16)c.w;
    } else {
#pragma unroll
        for (int e = 0; e < 8; ++e) {
            int i = e8 + e;
            hv[e] = (_Float16)((i < 300) ? emb[row + i] : 0.f);
        }
    }
    *reinterpret_cast<half8*>(X + (long)g * XROW + e8) = hv;
}

// ---------------- conv as MFMA GEMM ----------------
// r[(s,b,l), o] = tanh(conv_b[o] + sum_{k,kk} X[(s,b,l+k-1),kk] * whT[k][o][kk])
// Block: 32 rows x 304 cols, 256 threads (4 waves), wave w owns n-tiles w*5..
// Chunks m in [0,30): k = m/10, kk0 = (m%10)*32. Double-buffered LDS + reg prefetch.
__global__ __launch_bounds__(256, 2) void kc_conv(
    const _Float16* __restrict__ X, const _Float16* __restrict__ whT,
    const float* __restrict__ conv_b, float* __restrict__ r1, float* __restrict__ r2)
{
    int row0 = blockIdx.x * 32;
    int tid = threadIdx.x;
    int w = tid >> 6, lane = tid & 63, q = lane >> 4, jcol = lane & 15;

    __shared__ __align__(16) _Float16 At[2][32 * 40];
    __shared__ __align__(16) _Float16 Bt[2][304 * 40];

    // staging indices
    int ar = tid >> 2;             // A: row (tid<128)
    int ae8 = (tid & 3) * 8;       // A: k-offset
    int al = (row0 + ar) % 48;     // l for this A row

    half8 avP[2];
    half8 bvP[2][5];

    auto zero8 = []() { half8 z; for (int e = 0; e < 8; ++e) z[e] = (_Float16)0.f; return z; };

    auto loadA = [&](int m, half8& dst) {
        int k = m / 10, kk0 = (m - k * 10) * 32;
        int srcl = al + k - 1;
        if (tid < 128 && srcl >= 0 && srcl < 48)
            dst = *reinterpret_cast<const half8*>(X + (long)(row0 + ar + k - 1) * XROW + kk0 + ae8);
        else
            dst = zero8();
    };
    auto loadB = [&](int m, half8* dst) {
        int k = m / 10, kk0 = (m - k * 10) * 32;
#pragma unroll
        for (int t = 0; t < 5; ++t) {
            int idx = tid + t * 256;
            if (idx < 1216) {
                int col = idx >> 2, e8 = (idx & 3) * 8;
                dst[t] = *reinterpret_cast<const half8*>(whT + ((long)k * 304 + col) * XROW + kk0 + e8);
            }
        }
    };
    auto store = [&](int buf, const half8& av, const half8* bv) {
        if (tid < 128) *reinterpret_cast<half8*>(&At[buf][ar * 40 + ae8]) = av;
#pragma unroll
        for (int t = 0; t < 5; ++t) {
            int idx = tid + t * 256;
            if (idx < 1216) {
                int col = idx >> 2, e8 = (idx & 3) * 8;
                *reinterpret_cast<half8*>(&Bt[buf][col * 40 + e8]) = bv[t];
            }
        }
    };

    loadA(0, avP[0]); loadB(0, bvP[0]);
    store(0, avP[0], bvP[0]);
    loadA(1, avP[1]); loadB(1, bvP[1]);
    __syncthreads();

    float4v acc[2][5];
#pragma unroll
    for (int mt = 0; mt < 2; ++mt)
#pragma unroll
        for (int nt = 0; nt < 5; ++nt) acc[mt][nt] = (float4v){0.f, 0.f, 0.f, 0.f};

    for (int m = 0; m < 30; ++m) {
        int cur = m & 1;
        if (m + 1 < 30) store((m + 1) & 1, avP[(m + 1) & 1], bvP[(m + 1) & 1]);
        if (m + 2 < 30) { loadA(m + 2, avP[m & 1]); loadB(m + 2, bvP[m & 1]); }

        half8 afr[2];
#pragma unroll
        for (int mt = 0; mt < 2; ++mt)
            afr[mt] = *reinterpret_cast<const half8*>(&At[cur][(mt * 16 + jcol) * 40 + q * 8]);
#pragma unroll
        for (int nt = 0; nt < 5; ++nt) {
            int ntg = w * 5 + nt;
            if (ntg < 19) {
                half8 bfr = *reinterpret_cast<const half8*>(&Bt[cur][(ntg * 16 + jcol) * 40 + q * 8]);
#pragma unroll
                for (int mt = 0; mt < 2; ++mt)
                    acc[mt][nt] = __builtin_amdgcn_mfma_f32_16x16x32_f16(afr[mt], bfr, acc[mt][nt], 0, 0, 0);
            }
        }
        __syncthreads();
    }

    // epilogue: bias + tanh, write fp32 r
#pragma unroll
    for (int nt = 0; nt < 5; ++nt) {
        int ntg = w * 5 + nt;
        if (ntg >= 19) continue;
        int n = ntg * 16 + jcol;
        if (n >= 300) continue;
        float bias = conv_b[n];
#pragma unroll
        for (int mt = 0; mt < 2; ++mt) {
#pragma unroll
            for (int r = 0; r < 4; ++r) {
                int g = row0 + mt * 16 + q * 4 + r;
                int s = g / 3072;
                int rem = g - s * 3072;
                float* rout = s ? r2 : r1;
                rout[(long)rem * 300 + n] = tanhf(acc[mt][nt][r] + bias);
            }
        }
    }
}

// ---------------------------------------------------------------------------
// K2 (MFMA): pre[b,i,j,f] = sum_e |r1-r2|*Wd + sum_e r1*r2*Wp  (no bias/tanh)
// Double-buffered Bt from pre-packed Bprep, 1 barrier/chunk, reg prefetch.
// ---------------------------------------------------------------------------
#define RS 312   // LDS row stride (halves) for r tiles

__global__ __launch_bounds__(256, 2) void k2_joint(
    const float* __restrict__ r1, const float* __restrict__ r2,
    const int* __restrict__ q1_len, const int* __restrict__ q2_len,
    const _Float16* __restrict__ Bprep,
    float* __restrict__ s1p, float* __restrict__ s2p)
{
    int b = blockIdx.y;
    int it = blockIdx.x / 3;
    int jt = blockIdx.x - it * 3;
    int tid = threadIdx.x;
    int q1l = q1_len[b], q2l = q2_len[b];
    long base1 = ((long)(b * 3 + jt) * 48 + it * 16) * 300;
    long base2 = ((long)(b * 3 + it) * 48 + jt * 16) * 300;
    bool active = (it * 16 < q1l) && (jt * 16 < q2l);
    if (!active) {
        for (int idx = tid; idx < 4800; idx += 256) {
            s1p[base1 + idx] = NEGP;
            s2p[base2 + idx] = NEGP;
        }
        return;
    }

    __shared__ __align__(16) _Float16 r1h[16 * RS];
    __shared__ __align__(16) _Float16 r2h[16 * RS];
    __shared__ __align__(16) _Float16 Bt[2][64 * 40];
    __shared__ __align__(16) float red[64 * 68];

    // stage r tiles -> fp16 LDS
    for (int idx = tid; idx < 4800; idx += 256) {
        int row = idx / 300;
        int e = idx - row * 300;
        r1h[row * RS + e] = (_Float16)r1[((long)(b * 48) + it * 16) * 300 + idx];
        r2h[row * RS + e] = (_Float16)r2[((long)(b * 48) + jt * 16) * 300 + idx];
    }
    for (int idx = tid; idx < 2 * 16 * (RS - 300); idx += 256) {
        int half = idx / (16 * (RS - 300));
        int rest = idx - half * 16 * (RS - 300);
        int row = rest / (RS - 300);
        int e = 300 + rest - row * (RS - 300);
        (half ? r2h : r1h)[row * RS + e] = (_Float16)0.f;
    }

    int w    = tid >> 6;
    int lane = tid & 63;
    int q    = lane >> 4;
    int jcol = lane & 15;
    int sf_l = tid >> 2;
    int sk8  = (tid & 3) * 8;

    half8 p[2];
    p[0] = *reinterpret_cast<const half8*>(Bprep + (long)tid * 8);
    *reinterpret_cast<half8*>(&Bt[0][sf_l * 40 + sk8]) = p[0];
    p[1] = *reinterpret_cast<const half8*>(Bprep + (long)(256 + tid) * 8);
    __syncthreads();

    float4v acc[4][4];

    for (int m = 0; m < 95; ++m) {
        int nc = m / 19, kc = m - nc * 19;
        if (kc == 0) {
#pragma unroll
            for (int mt = 0; mt < 4; ++mt)
#pragma unroll
                for (int nt = 0; nt < 4; ++nt) acc[mt][nt] = (float4v){0.f, 0.f, 0.f, 0.f};
        }
        if (m + 1 < 95) *reinterpret_cast<half8*>(&Bt[(m + 1) & 1][sf_l * 40 + sk8]) = p[(m + 1) & 1];
        if (m + 2 < 95) p[m & 1] = *reinterpret_cast<const half8*>(Bprep + ((long)(m + 2) * 256 + tid) * 8);

        const _Float16* Bc = Bt[m & 1];
        int k0q = kc * 32 + q * 8;
        int koff = (k0q < 304) ? k0q : (k0q - 304);
        const half8 rv2 = *reinterpret_cast<const half8*>(r2h + jcol * RS + koff);
        half8 afr[4];
#pragma unroll
        for (int mt = 0; mt < 4; ++mt) {
            const half8 rv1 = *reinterpret_cast<const half8*>(r1h + (w * 4 + mt) * RS + koff);
            if (k0q < 304) {
                half8 dsub = rv1 - rv2;
                short8 s;
                __builtin_memcpy(&s, &dsub, 16);
                s &= (short)0x7FFF;
                __builtin_memcpy(&afr[mt], &s, 16);
            } else {
                afr[mt] = rv1 * rv2;
            }
        }
        half8 bfr[4];
#pragma unroll
        for (int nt = 0; nt < 4; ++nt)
            bfr[nt] = *reinterpret_cast<const half8*>(Bc + (nt * 16 + jcol) * 40 + q * 8);
#pragma unroll
        for (int mt = 0; mt < 4; ++mt)
#pragma unroll
            for (int nt = 0; nt < 4; ++nt)
                acc[mt][nt] = __builtin_amdgcn_mfma_f32_16x16x32_f16(afr[mt], bfr[nt], acc[mt][nt], 0, 0, 0);

        if (kc == 18) {
            // ---- s1: max over valid j ----
#pragma unroll
            for (int mt = 0; mt < 4; ++mt) {
                int i_l = w * 4 + mt;
#pragma unroll
                for (int nt = 0; nt < 4; ++nt) {
                    float mx = NEGP;
#pragma unroll
                    for (int r = 0; r < 4; ++r) {
                        int j = q * 4 + r;
                        if (jt * 16 + j < q2l) mx = fmaxf(mx, acc[mt][nt][r]);
                    }
                    mx = fmaxf(mx, __shfl_xor(mx, 16));
                    mx = fmaxf(mx, __shfl_xor(mx, 32));
                    int f = nc * 64 + nt * 16 + jcol;
                    if (q == 0 && f < 300) s1p[base1 + i_l * 300 + f] = mx;
                }
            }
            // ---- s2: max over valid i, cross-wave via LDS ----
            __syncthreads();
#pragma unroll
            for (int nt = 0; nt < 4; ++nt) {
#pragma unroll
                for (int r = 0; r < 4; ++r) {
                    float mx = NEGP;
#pragma unroll
                    for (int mt = 0; mt < 4; ++mt) {
                        int i = it * 16 + w * 4 + mt;
                        if (i < q1l) mx = fmaxf(mx, acc[mt][nt][r]);
                    }
                    red[((w * 16) + q * 4 + r) * 68 + nt * 16 + jcol] = mx;
                }
            }
            __syncthreads();
            for (int vv = tid; vv < 1024; vv += 256) {
                int j = vv >> 6;
                int fcol = vv & 63;
                float mx = red[j * 68 + fcol];
                mx = fmaxf(mx, red[(16 + j) * 68 + fcol]);
                mx = fmaxf(mx, red[(32 + j) * 68 + fcol]);
                mx = fmaxf(mx, red[(48 + j) * 68 + fcol]);
                int f = nc * 64 + fcol;
                if (f < 300) s2p[base2 + (long)j * 300 + f] = mx;
            }
        }
        __syncthreads();
    }
}

// K3: s = tanh(bias + max over 3 tile-partials)
__global__ void k3_combine(const float* __restrict__ s1p, const float* __restrict__ s2p,
                           const float* __restrict__ fc0b,
                           float* __restrict__ s1, float* __restrict__ s2)
{
    int idx = blockIdx.x * 256 + threadIdx.x;
    if (idx >= 64 * 48 * 300) return;
    int b = idx / 14400;
    int lf = idx - b * 14400;
    int f = lf % 300;
    long p = (long)b * 43200 + lf;
    float m1v = fmaxf(fmaxf(s1p[p], s1p[p + 14400]), s1p[p + 28800]);
    float m2v = fmaxf(fmaxf(s2p[p], s2p[p + 14400]), s2p[p + 28800]);
    float bia = fc0b[f];
    s1[idx] = tanhf(m1v + bia);
    s2[idx] = tanhf(m2v + bia);
}

// K4: attention pooling per (side,b): one wave
__global__ __launch_bounds__(64) void k4_pool(
    const float* __restrict__ r1, const float* __restrict__ r2,
    const float* __restrict__ s1, const float* __restrict__ s2,
    const int* __restrict__ q1_len, const int* __restrict__ q2_len,
    const float* __restrict__ att_w, const float* __restrict__ att_b,
    float* __restrict__ h1, float* __restrict__ h2)
{
    int side = blockIdx.x >> 6;
    int b = blockIdx.x & 63;
    const float* r = (side ? r2 : r1) + (long)b * 48 * 300;
    const float* s = (side ? s2 : s1) + (long)b * 48 * 300;
    int len = (side ? q2_len : q1_len)[b];
    float* h = (side ? h2 : h1) + b * 300;
    int t = threadIdx.x;
    __shared__ float aL[48];
    float logit = 0.f;
    if (t < 48) {
        float acc = att_b[0];
        for (int e = 0; e < 300; ++e) acc += r[t * 300 + e] * att_w[e];
        for (int f = 0; f < 300; ++f) acc += s[t * 300 + f] * att_w[300 + f];
        logit = acc;
    }
    float ml = (t < len) ? logit : NEGP;
    float mx = ml;
#pragma unroll
    for (int off = 32; off >= 1; off >>= 1) mx = fmaxf(mx, __shfl_xor(mx, off));
    float ex = (t < len) ? __expf(logit - mx) : 0.f;
    float smv = ex;
#pragma unroll
    for (int off = 32; off >= 1; off >>= 1) smv += __shfl_xor(smv, off);
    if (t < 48) aL[t] = ex / smv;
    __syncthreads();
    for (int f = t; f < 300; f += 64) {
        float acc = 0.f;
        for (int l = 0; l < 48; ++l) acc += aL[l] * s[(long)l * 300 + f];
        h[f] = acc;
    }
}

// K5: final MLP per batch row
__global__ __launch_bounds__(256) void k5_mlp(
    const float* __restrict__ h1, const float* __restrict__ h2,
    const float* __restrict__ fc1w, const float* __restrict__ fc1b,
    const float* __restrict__ fc2w, const float* __restrict__ fc2b,
    float* __restrict__ out)
{
    int b = blockIdx.x;
    int t = threadIdx.x;
    __shared__ float hc[600];
    __shared__ float jl[300];
    for (int e = t; e < 600; e += 256)
        hc[e] = (e < 300) ? h1[b * 300 + e] : h2[b * 300 + e - 300];
    __syncthreads();
    for (int g = t; g < 300; g += 256) {
        float acc = fc1b[g];
        for (int e = 0; e < 600; ++e) acc += hc[e] * fc1w[g * 600 + e];
        jl[g] = tanhf(acc);
    }
    __syncthreads();
    int wvv = t >> 6, lane = t & 63;
    if (wvv < 2) {
        float acc = 0.f;
        for (int g = lane; g < 300; g += 64) acc += jl[g] * fc2w[wvv * 300 + g];
#pragma unroll
        for (int off = 32; off >= 1; off >>= 1) acc += __shfl_xor(acc, off);
        if (lane == 0) out[b * 2 + wvv] = acc + fc2b[wvv];
    }
}

extern "C" void kernel_launch(void* const* d_in, const int* in_sizes, int n_in,
                              void* d_out, int out_size, void* d_ws, size_t ws_size,
                              hipStream_t stream)
{
    const int*   q1     = (const int*)d_in[0];
    const int*   q2     = (const int*)d_in[1];
    const int*   q1_len = (const int*)d_in[2];
    const int*   q2_len = (const int*)d_in[3];
    const float* emb    = (const float*)d_in[4];
    const float* conv_w = (const float*)d_in[5];
    const float* conv_b = (const float*)d_in[6];
    const float* fc0_w  = (const float*)d_in[7];
    const float* fc0_b  = (const float*)d_in[8];
    const float* fc1_w  = (const float*)d_in[9];
    const float* fc1_b  = (const float*)d_in[10];
    const float* fc2_w  = (const float*)d_in[11];
    const float* fc2_b  = (const float*)d_in[12];
    const float* att_w  = (const float*)d_in[13];
    const float* att_b  = (const float*)d_in[14];

    float* ws  = (float*)d_ws;
    float* r1  = ws;
    float* r2  = ws + 921600;
    float* s1p = ws + 1843200;
    float* s2p = ws + 4608000;
    float* s1  = ws + 7372800;
    float* s2  = ws + 8294400;
    float* h1  = ws + 9216000;
    float* h2  = ws + 9235200;
    _Float16* X     = (_Float16*)(ws + 1843200);   // pre-k2 alias of s1p region
    _Float16* whT   = (_Float16*)(ws + 2826240);   // pre-k2 alias of s1p region
    _Float16* Bprep = (_Float16*)(ws + 9254400);
    float* out = (float*)d_out;

    hipLaunchKernelGGL(kp_w, dim3((3 * 304 * XROW + 255) / 256), dim3(256), 0, stream,
                       conv_w, whT);
    hipLaunchKernelGGL(kp_b, dim3(95), dim3(256), 0, stream, fc0_w, Bprep);
    hipLaunchKernelGGL(kp_x, dim3(6144 * (XROW / 8) / 256), dim3(256), 0, stream,
                       q1, q2, emb, X);
    hipLaunchKernelGGL(kc_conv, dim3(192), dim3(256), 0, stream,
                       X, whT, conv_b, r1, r2);
    hipLaunchKernelGGL(k2_joint, dim3(9, 64), dim3(256), 0, stream,
                       r1, r2, q1_len, q2_len, Bprep, s1p, s2p);
    hipLaunchKernelGGL(k3_combine, dim3((64 * 48 * 300 + 255) / 256), dim3(256), 0, stream,
                       s1p, s2p, fc0_b, s1, s2);
    hipLaunchKernelGGL(k4_pool, dim3(128), dim3(64), 0, stream,
                       r1, r2, s1, s2, q1_len, q2_len, att_w, att_b, h1, h2);
    hipLaunchKernelGGL(k5_mlp, dim3(64), dim3(256), 0, stream,
                       h1, h2, fc1_w, fc1_b, fc2_w, fc2_b, out);
}

// Round 4
// 317.248 us; speedup vs baseline: 2.7364x; 2.7364x over previous
//
#include <hip/hip_runtime.h>
#include <math.h>

#define B_  64
#define L_  48
#define E_  300
#define F0_ 300
#define NEGP (-1e30f)
#define XROW 320      // X / whT row stride in halves (640B, 16B aligned)

typedef __attribute__((ext_vector_type(8))) _Float16 half8;
typedef __attribute__((ext_vector_type(8))) short   short8;
typedef __attribute__((ext_vector_type(4))) float   float4v;

// -------- workspace layout (float offsets) --------
// r1    : 0        .. 921600      (B*L*E) fp32
// r2    : 921600   .. 1843200
// s1p   : 1843200  .. 4608000     (B*3*48*300) pre-tanh partial max over j per j-tile
//   X   : 1843200  .. 2826240     [pre-k2 alias] 6144x320 fp16 gathered embeddings
//   whT : 2826240  .. 2972160     [pre-k2 alias] 3x304x320 fp16 conv weights
// s2p   : 4608000  .. 7372800
// s1    : 7372800  .. 8294400
// s2    : 8294400  .. 9216000
// h1    : 9216000  .. 9235200
// h2    : 9235200  .. 9254400
// Bprep : 9254400  .. 9351680     95x256x8 fp16 pre-packed fc0_w chunks

// whT[k][o][kk] = conv_w[(o*300+kk)*3+k]  (o<300, kk<300 else 0)
__global__ void kp_w(const float* __restrict__ conv_w, _Float16* __restrict__ whT) {
    int idx = blockIdx.x * 256 + threadIdx.x;
    if (idx >= 3 * 304 * XROW) return;
    int k = idx / (304 * XROW);
    int rest = idx - k * 304 * XROW;
    int o = rest / XROW;
    int kk = rest - o * XROW;
    float v = 0.f;
    if (o < 300 && kk < 300) v = conv_w[(o * 300 + kk) * 3 + k];
    whT[idx] = (_Float16)v;
}

// Bprep[m][tid][e]: exact half8 thread tid stages to Bt for chunk m of k2.
// m = nc*19+kc ; f = nc*64 + tid/4 ; k = kc*32 + (tid%4)*8 + e
// K axis: [0,300)=d-part, [304,604)=p-part (e=k-304), else 0.
__global__ void kp_b(const float* __restrict__ fc0w, _Float16* __restrict__ Bprep) {
    int m = blockIdx.x;
    int tid = threadIdx.x;
    int nc = m / 19, kc = m - nc * 19;
    int f = nc * 64 + (tid >> 2);
    int kbase = kc * 32 + (tid & 3) * 8;
    half8 hv;
#pragma unroll
    for (int e = 0; e < 8; ++e) {
        int k = kbase + e;
        float v = 0.f;
        if (f < 300) {
            if (k < 300) v = fc0w[f * 600 + k];
            else if (k >= 304 && k < 604) v = fc0w[f * 600 + k - 4];
        }
        hv[e] = (_Float16)v;
    }
    *reinterpret_cast<half8*>(Bprep + ((long)m * 256 + tid) * 8) = hv;
}

// X[(s,b,l)][i] = fp16(emb[q_s[b,l], i])  (i<300 else 0); row stride XROW
__global__ void kp_x(const int* __restrict__ q1, const int* __restrict__ q2,
                     const float* __restrict__ emb, _Float16* __restrict__ X) {
    int u = blockIdx.x * 256 + threadIdx.x;
    if (u >= 6144 * (XROW / 8)) return;
    int g = u / (XROW / 8);
    int e8 = (u - g * (XROW / 8)) * 8;
    int s = g / 3072;
    int rem = g - s * 3072;
    long row = (long)((s ? q2 : q1)[rem]) * 300;
    half8 hv;
    if (e8 + 7 < 300) {
        float4 a = *reinterpret_cast<const float4*>(emb + row + e8);
        float4 c = *reinterpret_cast<const float4*>(emb + row + e8 + 4);
        hv[0] = (_Float16)a.x; hv[1] = (_Float16)a.y; hv[2] = (_Float16)a.z; hv[3] = (_Float16)a.w;
        hv[4] = (_Float16)c.x; hv[5] = (_Float16)c.y; hv[6] = (_Float16)c.z; hv[7] = (_Float16)c.w;
    } else {
#pragma unroll
        for (int e = 0; e < 8; ++e) {
            int i = e8 + e;
            hv[e] = (_Float16)((i < 300) ? emb[row + i] : 0.f);
        }
    }
    *reinterpret_cast<half8*>(X + (long)g * XROW + e8) = hv;
}

// ---------------- conv as MFMA GEMM ----------------
// Single-buffer LDS, 2 barriers/chunk; next chunk prefetched into NAMED
// registers (no dynamic register-array indexing) before barrier1.
__global__ __launch_bounds__(256, 3) void kc_conv(
    const _Float16* __restrict__ X, const _Float16* __restrict__ whT,
    const float* __restrict__ conv_b, float* __restrict__ r1, float* __restrict__ r2)
{
    int row0 = blockIdx.x * 32;
    int tid = threadIdx.x;
    int w = tid >> 6, lane = tid & 63, q = lane >> 4, jcol = lane & 15;

    __shared__ __align__(16) _Float16 At[32 * 40];
    __shared__ __align__(16) _Float16 Bt[304 * 40];

    int ar = tid >> 2;
    int ae8 = (tid & 3) * 8;
    int al = (row0 + ar) % 48;

    auto zero8 = []() { half8 z; for (int e = 0; e < 8; ++e) z[e] = (_Float16)0.f; return z; };

    auto loadA = [&](int m, half8& dst) {
        int k = m / 10, kk0 = (m - k * 10) * 32;
        int srcl = al + k - 1;
        if (tid < 128 && srcl >= 0 && srcl < 48)
            dst = *reinterpret_cast<const half8*>(X + (long)(row0 + ar + k - 1) * XROW + kk0 + ae8);
        else
            dst = zero8();
    };
    auto loadB = [&](int m, half8* dst) {
        int k = m / 10, kk0 = (m - k * 10) * 32;
#pragma unroll
        for (int t = 0; t < 5; ++t) {
            int idx = tid + t * 256;
            if (idx < 1216) {
                int col = idx >> 2, e8 = (idx & 3) * 8;
                dst[t] = *reinterpret_cast<const half8*>(whT + ((long)k * 304 + col) * XROW + kk0 + e8);
            }
        }
    };
    auto store = [&](const half8& av, const half8* bv) {
        if (tid < 128) *reinterpret_cast<half8*>(&At[ar * 40 + ae8]) = av;
#pragma unroll
        for (int t = 0; t < 5; ++t) {
            int idx = tid + t * 256;
            if (idx < 1216) {
                int col = idx >> 2, e8 = (idx & 3) * 8;
                *reinterpret_cast<half8*>(&Bt[col * 40 + e8]) = bv[t];
            }
        }
    };

    half8 pva; half8 pvb[5];
    loadA(0, pva); loadB(0, pvb);

    float4v acc[2][5];
#pragma unroll
    for (int mt = 0; mt < 2; ++mt)
#pragma unroll
        for (int nt = 0; nt < 5; ++nt) acc[mt][nt] = (float4v){0.f, 0.f, 0.f, 0.f};

    for (int m = 0; m < 30; ++m) {
        half8 pvan; half8 pvbn[5];
        if (m + 1 < 30) {
            loadA(m + 1, pvan); loadB(m + 1, pvbn);
        } else {
            pvan = zero8();
#pragma unroll
            for (int t = 0; t < 5; ++t) pvbn[t] = pvan;
        }
        __syncthreads();
        store(pva, pvb);
        __syncthreads();

        half8 afr[2];
#pragma unroll
        for (int mt = 0; mt < 2; ++mt)
            afr[mt] = *reinterpret_cast<const half8*>(&At[(mt * 16 + jcol) * 40 + q * 8]);
#pragma unroll
        for (int nt = 0; nt < 5; ++nt) {
            int ntg = w * 5 + nt;
            if (ntg < 19) {
                half8 bfr = *reinterpret_cast<const half8*>(&Bt[(ntg * 16 + jcol) * 40 + q * 8]);
#pragma unroll
                for (int mt = 0; mt < 2; ++mt)
                    acc[mt][nt] = __builtin_amdgcn_mfma_f32_16x16x32_f16(afr[mt], bfr, acc[mt][nt], 0, 0, 0);
            }
        }
        pva = pvan;
#pragma unroll
        for (int t = 0; t < 5; ++t) pvb[t] = pvbn[t];
    }

#pragma unroll
    for (int nt = 0; nt < 5; ++nt) {
        int ntg = w * 5 + nt;
        if (ntg >= 19) continue;
        int n = ntg * 16 + jcol;
        if (n >= 300) continue;
        float bias = conv_b[n];
#pragma unroll
        for (int mt = 0; mt < 2; ++mt) {
#pragma unroll
            for (int r = 0; r < 4; ++r) {
                int g = row0 + mt * 16 + q * 4 + r;
                int s = g / 3072;
                int rem = g - s * 3072;
                float* rout = s ? r2 : r1;
                rout[(long)rem * 300 + n] = tanhf(acc[mt][nt][r] + bias);
            }
        }
    }
}

// ---------------------------------------------------------------------------
// K2 (MFMA): R2-proven structure (nc-outer / kc-inner, single Bt, 2 barriers),
// B staged from pre-packed Bprep via named prefetch registers pv/pvn.
// ---------------------------------------------------------------------------
#define RS 312

__global__ __launch_bounds__(256, 3) void k2_joint(
    const float* __restrict__ r1, const float* __restrict__ r2,
    const int* __restrict__ q1_len, const int* __restrict__ q2_len,
    const _Float16* __restrict__ Bprep,
    float* __restrict__ s1p, float* __restrict__ s2p)
{
    int b = blockIdx.y;
    int it = blockIdx.x / 3;
    int jt = blockIdx.x - it * 3;
    int tid = threadIdx.x;
    int q1l = q1_len[b], q2l = q2_len[b];
    long base1 = ((long)(b * 3 + jt) * 48 + it * 16) * 300;
    long base2 = ((long)(b * 3 + it) * 48 + jt * 16) * 300;
    bool active = (it * 16 < q1l) && (jt * 16 < q2l);
    if (!active) {
        for (int idx = tid; idx < 4800; idx += 256) {
            s1p[base1 + idx] = NEGP;
            s2p[base2 + idx] = NEGP;
        }
        return;
    }

    __shared__ __align__(16) _Float16 r1h[16 * RS];
    __shared__ __align__(16) _Float16 r2h[16 * RS];
    __shared__ __align__(16) unsigned char bred[64 * 68 * 4];  // union Bt/red
    _Float16* Bt = (_Float16*)bred;
    float*    red = (float*)bred;

    for (int idx = tid; idx < 4800; idx += 256) {
        int row = idx / 300;
        int e = idx - row * 300;
        r1h[row * RS + e] = (_Float16)r1[((long)(b * 48) + it * 16) * 300 + idx];
        r2h[row * RS + e] = (_Float16)r2[((long)(b * 48) + jt * 16) * 300 + idx];
    }
    for (int idx = tid; idx < 2 * 16 * (RS - 300); idx += 256) {
        int half = idx / (16 * (RS - 300));
        int rest = idx - half * 16 * (RS - 300);
        int row = rest / (RS - 300);
        int e = 300 + rest - row * (RS - 300);
        (half ? r2h : r1h)[row * RS + e] = (_Float16)0.f;
    }

    int w    = tid >> 6;
    int lane = tid & 63;
    int q    = lane >> 4;
    int jcol = lane & 15;
    int sf_l = tid >> 2;
    int sk8  = (tid & 3) * 8;

    half8 pv = *reinterpret_cast<const half8*>(Bprep + (long)tid * 8);   // chunk 0

    float4v acc[4][4];

    for (int nc = 0; nc < 5; ++nc) {
#pragma unroll
        for (int mt = 0; mt < 4; ++mt)
#pragma unroll
            for (int nt = 0; nt < 4; ++nt) acc[mt][nt] = (float4v){0.f, 0.f, 0.f, 0.f};

        for (int kc = 0; kc < 19; ++kc) {
            int m = nc * 19 + kc;
            half8 pvn;
            if (m + 1 < 95)
                pvn = *reinterpret_cast<const half8*>(Bprep + ((long)(m + 1) * 256 + tid) * 8);
            else
                pvn = pv;
            __syncthreads();   // prev chunk readers done with Bt (also red users)
            *reinterpret_cast<half8*>(Bt + sf_l * 40 + sk8) = pv;
            __syncthreads();   // Bt ready

            int k0q = kc * 32 + q * 8;
            int koff = (k0q < 304) ? k0q : (k0q - 304);
            const half8 rv2 = *reinterpret_cast<const half8*>(r2h + jcol * RS + koff);
            half8 afr[4];
#pragma unroll
            for (int mt = 0; mt < 4; ++mt) {
                const half8 rv1 = *reinterpret_cast<const half8*>(r1h + (w * 4 + mt) * RS + koff);
                if (k0q < 304) {
                    half8 dsub = rv1 - rv2;
                    short8 s;
                    __builtin_memcpy(&s, &dsub, 16);
                    s &= (short)0x7FFF;
                    __builtin_memcpy(&afr[mt], &s, 16);
                } else {
                    afr[mt] = rv1 * rv2;
                }
            }
            half8 bfr[4];
#pragma unroll
            for (int nt = 0; nt < 4; ++nt)
                bfr[nt] = *reinterpret_cast<const half8*>(Bt + (nt * 16 + jcol) * 40 + q * 8);
#pragma unroll
            for (int mt = 0; mt < 4; ++mt)
#pragma unroll
                for (int nt = 0; nt < 4; ++nt)
                    acc[mt][nt] = __builtin_amdgcn_mfma_f32_16x16x32_f16(afr[mt], bfr[nt], acc[mt][nt], 0, 0, 0);
            pv = pvn;
        }

        // ---- s1: max over valid j ----
#pragma unroll
        for (int mt = 0; mt < 4; ++mt) {
            int i_l = w * 4 + mt;
#pragma unroll
            for (int nt = 0; nt < 4; ++nt) {
                float mx = NEGP;
#pragma unroll
                for (int r = 0; r < 4; ++r) {
                    int j = q * 4 + r;
                    if (jt * 16 + j < q2l) mx = fmaxf(mx, acc[mt][nt][r]);
                }
                mx = fmaxf(mx, __shfl_xor(mx, 16));
                mx = fmaxf(mx, __shfl_xor(mx, 32));
                int f = nc * 64 + nt * 16 + jcol;
                if (q == 0 && f < 300) s1p[base1 + i_l * 300 + f] = mx;
            }
        }

        // ---- s2: max over valid i, cross-wave via LDS (red aliases Bt) ----
        __syncthreads();
#pragma unroll
        for (int nt = 0; nt < 4; ++nt) {
#pragma unroll
            for (int r = 0; r < 4; ++r) {
                float mx = NEGP;
#pragma unroll
                for (int mt = 0; mt < 4; ++mt) {
                    int i = it * 16 + w * 4 + mt;
                    if (i < q1l) mx = fmaxf(mx, acc[mt][nt][r]);
                }
                red[((w * 16) + q * 4 + r) * 68 + nt * 16 + jcol] = mx;
            }
        }
        __syncthreads();
        for (int vv = tid; vv < 1024; vv += 256) {
            int j = vv >> 6;
            int fcol = vv & 63;
            float mx = red[j * 68 + fcol];
            mx = fmaxf(mx, red[(16 + j) * 68 + fcol]);
            mx = fmaxf(mx, red[(32 + j) * 68 + fcol]);
            mx = fmaxf(mx, red[(48 + j) * 68 + fcol]);
            int f = nc * 64 + fcol;
            if (f < 300) s2p[base2 + (long)j * 300 + f] = mx;
        }
    }
}

// K3: s = tanh(bias + max over 3 tile-partials)
__global__ void k3_combine(const float* __restrict__ s1p, const float* __restrict__ s2p,
                           const float* __restrict__ fc0b,
                           float* __restrict__ s1, float* __restrict__ s2)
{
    int idx = blockIdx.x * 256 + threadIdx.x;
    if (idx >= 64 * 48 * 300) return;
    int b = idx / 14400;
    int lf = idx - b * 14400;
    int f = lf % 300;
    long p = (long)b * 43200 + lf;
    float m1v = fmaxf(fmaxf(s1p[p], s1p[p + 14400]), s1p[p + 28800]);
    float m2v = fmaxf(fmaxf(s2p[p], s2p[p + 14400]), s2p[p + 28800]);
    float bia = fc0b[f];
    s1[idx] = tanhf(m1v + bia);
    s2[idx] = tanhf(m2v + bia);
}

// K4: attention pooling per (side,b): one wave
__global__ __launch_bounds__(64) void k4_pool(
    const float* __restrict__ r1, const float* __restrict__ r2,
    const float* __restrict__ s1, const float* __restrict__ s2,
    const int* __restrict__ q1_len, const int* __restrict__ q2_len,
    const float* __restrict__ att_w, const float* __restrict__ att_b,
    float* __restrict__ h1, float* __restrict__ h2)
{
    int side = blockIdx.x >> 6;
    int b = blockIdx.x & 63;
    const float* r = (side ? r2 : r1) + (long)b * 48 * 300;
    const float* s = (side ? s2 : s1) + (long)b * 48 * 300;
    int len = (side ? q2_len : q1_len)[b];
    float* h = (side ? h2 : h1) + b * 300;
    int t = threadIdx.x;
    __shared__ float aL[48];
    float logit = 0.f;
    if (t < 48) {
        float acc = att_b[0];
        for (int e = 0; e < 300; ++e) acc += r[t * 300 + e] * att_w[e];
        for (int f = 0; f < 300; ++f) acc += s[t * 300 + f] * att_w[300 + f];
        logit = acc;
    }
    float ml = (t < len) ? logit : NEGP;
    float mx = ml;
#pragma unroll
    for (int off = 32; off >= 1; off >>= 1) mx = fmaxf(mx, __shfl_xor(mx, off));
    float ex = (t < len) ? __expf(logit - mx) : 0.f;
    float smv = ex;
#pragma unroll
    for (int off = 32; off >= 1; off >>= 1) smv += __shfl_xor(smv, off);
    if (t < 48) aL[t] = ex / smv;
    __syncthreads();
    for (int f = t; f < 300; f += 64) {
        float acc = 0.f;
        for (int l = 0; l < 48; ++l) acc += aL[l] * s[(long)l * 300 + f];
        h[f] = acc;
    }
}

// K5: final MLP per batch row
__global__ __launch_bounds__(256) void k5_mlp(
    const float* __restrict__ h1, const float* __restrict__ h2,
    const float* __restrict__ fc1w, const float* __restrict__ fc1b,
    const float* __restrict__ fc2w, const float* __restrict__ fc2b,
    float* __restrict__ out)
{
    int b = blockIdx.x;
    int t = threadIdx.x;
    __shared__ float hc[600];
    __shared__ float jl[300];
    for (int e = t; e < 600; e += 256)
        hc[e] = (e < 300) ? h1[b * 300 + e] : h2[b * 300 + e - 300];
    __syncthreads();
    for (int g = t; g < 300; g += 256) {
        float acc = fc1b[g];
        for (int e = 0; e < 600; ++e) acc += hc[e] * fc1w[g * 600 + e];
        jl[g] = tanhf(acc);
    }
    __syncthreads();
    int wvv = t >> 6, lane = t & 63;
    if (wvv < 2) {
        float acc = 0.f;
        for (int g = lane; g < 300; g += 64) acc += jl[g] * fc2w[wvv * 300 + g];
#pragma unroll
        for (int off = 32; off >= 1; off >>= 1) acc += __shfl_xor(acc, off);
        if (lane == 0) out[b * 2 + wvv] = acc + fc2b[wvv];
    }
}

extern "C" void kernel_launch(void* const* d_in, const int* in_sizes, int n_in,
                              void* d_out, int out_size, void* d_ws, size_t ws_size,
                              hipStream_t stream)
{
    const int*   q1     = (const int*)d_in[0];
    const int*   q2     = (const int*)d_in[1];
    const int*   q1_len = (const int*)d_in[2];
    const int*   q2_len = (const int*)d_in[3];
    const float* emb    = (const float*)d_in[4];
    const float* conv_w = (const float*)d_in[5];
    const float* conv_b = (const float*)d_in[6];
    const float* fc0_w  = (const float*)d_in[7];
    const float* fc0_b  = (const float*)d_in[8];
    const float* fc1_w  = (const float*)d_in[9];
    const float* fc1_b  = (const float*)d_in[10];
    const float* fc2_w  = (const float*)d_in[11];
    const float* fc2_b  = (const float*)d_in[12];
    const float* att_w  = (const float*)d_in[13];
    const float* att_b  = (const float*)d_in[14];

    float* ws  = (float*)d_ws;
    float* r1  = ws;
    float* r2  = ws + 921600;
    float* s1p = ws + 1843200;
    float* s2p = ws + 4608000;
    float* s1  = ws + 7372800;
    float* s2  = ws + 8294400;
    float* h1  = ws + 9216000;
    float* h2  = ws + 9235200;
    _Float16* X     = (_Float16*)(ws + 1843200);   // pre-k2 alias of s1p region
    _Float16* whT   = (_Float16*)(ws + 2826240);   // pre-k2 alias of s1p region
    _Float16* Bprep = (_Float16*)(ws + 9254400);
    float* out = (float*)d_out;

    hipLaunchKernelGGL(kp_w, dim3((3 * 304 * XROW + 255) / 256), dim3(256), 0, stream,
                       conv_w, whT);
    hipLaunchKernelGGL(kp_b, dim3(95), dim3(256), 0, stream, fc0_w, Bprep);
    hipLaunchKernelGGL(kp_x, dim3(6144 * (XROW / 8) / 256), dim3(256), 0, stream,
                       q1, q2, emb, X);
    hipLaunchKernelGGL(kc_conv, dim3(192), dim3(256), 0, stream,
                       X, whT, conv_b, r1, r2);
    hipLaunchKernelGGL(k2_joint, dim3(9, 64), dim3(256), 0, stream,
                       r1, r2, q1_len, q2_len, Bprep, s1p, s2p);
    hipLaunchKernelGGL(k3_combine, dim3((64 * 48 * 300 + 255) / 256), dim3(256), 0, stream,
                       s1p, s2p, fc0_b, s1, s2);
    hipLaunchKernelGGL(k4_pool, dim3(128), dim3(64), 0, stream,
                       r1, r2, s1, s2, q1_len, q2_len, att_w, att_b, h1, h2);
    hipLaunchKernelGGL(k5_mlp, dim3(64), dim3(256), 0, stream,
                       h1, h2, fc1_w, fc1_b, fc2_w, fc2_b, out);
}

// Round 5
// 288.886 us; speedup vs baseline: 3.0050x; 1.0982x over previous
//
#include <hip/hip_runtime.h>
#include <math.h>

#define B_  64
#define L_  48
#define E_  300
#define F0_ 300
#define NEGP (-1e30f)
#define XROW 320      // X row stride in halves (640B, 16B aligned)
#define RS  312       // k2 r-tile LDS row stride (halves)

typedef __attribute__((ext_vector_type(8))) _Float16 half8;
typedef __attribute__((ext_vector_type(8))) short   short8;
typedef __attribute__((ext_vector_type(4))) float   float4v;

// -------- workspace layout (float offsets) --------
// r1    : 0        .. 921600      (B*L*E) fp32
// r2    : 921600   .. 1843200
// s1p   : 1843200  .. 4608000     (B*3*48*300) pre-tanh partial max over j per j-tile
//   X   : 1843200  .. 2826240     [pre-k2 alias] 6144x320 fp16 gathered embeddings
//   Bc  : 2826240  .. 2972160     [pre-k2 alias] 30x19x64x8 fp16 conv-W frags
// s2p   : 4608000  .. 7372800
// s1    : 7372800  .. 8294400
// s2    : 8294400  .. 9216000
// h1    : 9216000  .. 9235200
// h2    : 9235200  .. 9254400
// Bp2   : 9254400  .. 9351680     95x4x64x8 fp16 fc0_w frags (per-lane order)
// fc1wT : 9351680  .. 9442880     600x304 fp16 transposed fc1_w

// ---------------- fused prep kernel ----------------
// sections (in half8 units): Bp2 24320 | Bc 36480 | fc1wT 22800 | X 245760
__global__ __launch_bounds__(256) void kp_all(
    const int* __restrict__ q1, const int* __restrict__ q2,
    const float* __restrict__ emb, const float* __restrict__ conv_w,
    const float* __restrict__ fc0w, const float* __restrict__ fc1w,
    _Float16* __restrict__ Bp2, _Float16* __restrict__ Bc,
    _Float16* __restrict__ fc1wT, _Float16* __restrict__ X)
{
    int u = blockIdx.x * 256 + threadIdx.x;
    if (u < 24320) {
        // Bp2[m][nt][lane][8]; m=nc*19+kc; f=nc*64+nt*16+(lane&15); k=kc*32+(lane>>4)*8+j
        int m = u >> 8, rest = u & 255;
        int nt = rest >> 6, lane = rest & 63;
        int f = (m / 19) * 64 + nt * 16 + (lane & 15);
        int kb = (m % 19) * 32 + ((lane >> 4) << 3);
        half8 hv;
#pragma unroll
        for (int j = 0; j < 8; ++j) {
            int k = kb + j;
            float v = 0.f;
            if (f < 300) {
                if (k < 300) v = fc0w[f * 600 + k];
                else if (k >= 304 && k < 604) v = fc0w[f * 600 + k - 4];
            }
            hv[j] = (_Float16)v;
        }
        *reinterpret_cast<half8*>(Bp2 + (long)u * 8) = hv;
    } else if (u < 60800) {
        // Bc[m][ntg][lane][8]; k=m/10; kk=(m%10)*32+(lane>>4)*8+j; o=ntg*16+(lane&15)
        int v = u - 24320;
        int m = v / 1216, rest = v - m * 1216;
        int ntg = rest >> 6, lane = rest & 63;
        int o = ntg * 16 + (lane & 15);
        int kkb = (m % 10) * 32 + ((lane >> 4) << 3);
        int k = m / 10;
        half8 hv;
#pragma unroll
        for (int j = 0; j < 8; ++j) {
            int kk = kkb + j;
            float val = 0.f;
            if (o < 300 && kk < 300) val = conv_w[(o * 300 + kk) * 3 + k];
            hv[j] = (_Float16)val;
        }
        *reinterpret_cast<half8*>(Bc + (long)v * 8) = hv;
    } else if (u < 83600) {
        // fc1wT[e][g] = fc1w[g][e], fp16, 304-padded
        int v = u - 60800;
        int e = v / 38;
        int g8 = (v - e * 38) * 8;
        half8 hv;
#pragma unroll
        for (int j = 0; j < 8; ++j) {
            int g = g8 + j;
            hv[j] = (_Float16)((g < 300) ? fc1w[g * 600 + e] : 0.f);
        }
        *reinterpret_cast<half8*>(fc1wT + (long)e * 304 + g8) = hv;
    } else if (u < 329360) {
        // X[(s,b,l)][i] = fp16(emb[q,i]), 320-padded
        int v = u - 83600;
        int g = v / 40;
        int e8 = (v - g * 40) * 8;
        int s = g / 3072;
        int rem = g - s * 3072;
        long row = (long)((s ? q2 : q1)[rem]) * 300;
        half8 hv;
        if (e8 + 7 < 300) {
            float4 a = *reinterpret_cast<const float4*>(emb + row + e8);
            float4 c = *reinterpret_cast<const float4*>(emb + row + e8 + 4);
            hv[0] = (_Float16)a.x; hv[1] = (_Float16)a.y; hv[2] = (_Float16)a.z; hv[3] = (_Float16)a.w;
            hv[4] = (_Float16)c.x; hv[5] = (_Float16)c.y; hv[6] = (_Float16)c.z; hv[7] = (_Float16)c.w;
        } else {
#pragma unroll
            for (int j = 0; j < 8; ++j) {
                int i = e8 + j;
                hv[j] = (_Float16)((i < 300) ? emb[row + i] : 0.f);
            }
        }
        *reinterpret_cast<half8*>(X + (long)g * XROW + e8) = hv;
    }
}

// ---------------- conv as barrier-free MFMA GEMM ----------------
// 1 wave per block, 16 rows x 304 cols, K = 30 chunks of 32.
// A from X (global), B-frags from pre-laid Bc (global, coalesced). No LDS.
__global__ __launch_bounds__(64) void kc_conv(
    const _Float16* __restrict__ X, const _Float16* __restrict__ Bc,
    const float* __restrict__ conv_b, float* __restrict__ r1, float* __restrict__ r2)
{
    int row0 = blockIdx.x * 16;
    int lane = threadIdx.x;
    int q = lane >> 4, jcol = lane & 15;
    int grow = row0 + jcol;           // this lane's A row (m-index)
    int l = grow % 48;

    auto zero8 = []() { half8 z; for (int e = 0; e < 8; ++e) z[e] = (_Float16)0.f; return z; };
    auto loadA = [&](int m) -> half8 {
        int k = m / 10, kk0 = (m - k * 10) * 32;
        int srcl = l + k - 1;
        if (srcl >= 0 && srcl < 48)
            return *reinterpret_cast<const half8*>(X + (long)(grow + k - 1) * XROW + kk0 + q * 8);
        return zero8();
    };

    float4v acc[19];
#pragma unroll
    for (int nt = 0; nt < 19; ++nt) acc[nt] = (float4v){0.f, 0.f, 0.f, 0.f};

    half8 a_cur = loadA(0);
    for (int m = 0; m < 30; ++m) {
        half8 a_nxt = (m < 29) ? loadA(m + 1) : a_cur;
        const _Float16* bchunk = Bc + (long)m * 19 * 512;   // 64*8 = 512 halves per ntg
#pragma unroll
        for (int ntg = 0; ntg < 19; ++ntg) {
            half8 bfr = *reinterpret_cast<const half8*>(bchunk + (long)ntg * 512 + lane * 8);
            acc[ntg] = __builtin_amdgcn_mfma_f32_16x16x32_f16(a_cur, bfr, acc[ntg], 0, 0, 0);
        }
        a_cur = a_nxt;
    }

    // epilogue: row = q*4+r, col = ntg*16+jcol
#pragma unroll
    for (int ntg = 0; ntg < 19; ++ntg) {
        int n = ntg * 16 + jcol;
        if (n >= 300) continue;
        float bias = conv_b[n];
#pragma unroll
        for (int r = 0; r < 4; ++r) {
            int g = row0 + q * 4 + r;
            int s = g / 3072;
            int rem = g - s * 3072;
            float* rout = s ? r2 : r1;
            rout[(long)rem * 300 + n] = tanhf(acc[ntg][r] + bias);
        }
    }
}

// ---------------------------------------------------------------------------
// K2: barrier-free K-loop. Block = (b, it, jt, nc): 16i x 16j pairs, 64 f.
// A-frags generated from LDS r-tiles (read-only); B-frags direct from Bp2
// (coalesced 1KB loads), prefetched one chunk ahead into named registers.
// ---------------------------------------------------------------------------
__global__ __launch_bounds__(256, 3) void k2_joint(
    const float* __restrict__ r1, const float* __restrict__ r2,
    const int* __restrict__ q1_len, const int* __restrict__ q2_len,
    const _Float16* __restrict__ Bp2,
    float* __restrict__ s1p, float* __restrict__ s2p)
{
    int x = blockIdx.x;               // 0..44
    int tile = x / 5, nc = x - tile * 5;
    int it = tile / 3, jt = tile - it * 3;
    int b = blockIdx.y;
    int tid = threadIdx.x;
    int q1l = q1_len[b], q2l = q2_len[b];
    long base1 = ((long)(b * 3 + jt) * 48 + it * 16) * 300;
    long base2 = ((long)(b * 3 + it) * 48 + jt * 16) * 300;
    bool active = (it * 16 < q1l) && (jt * 16 < q2l);
    if (!active) {
        for (int idx = tid; idx < 2048; idx += 256) {
            int side = idx >> 10;
            int rest = idx & 1023;
            int row = rest >> 6;
            int f = nc * 64 + (rest & 63);
            if (f < 300) (side ? s2p + base2 : s1p + base1)[row * 300 + f] = NEGP;
        }
        return;
    }

    __shared__ __align__(16) unsigned char smraw[16 * RS * 2 * 2];  // 19968 B
    _Float16* r1h = (_Float16*)smraw;
    _Float16* r2h = r1h + 16 * RS;
    float* red = (float*)smraw;       // union, used in epilogue only (64x68)

    // stage r tiles -> fp16 LDS (vectorized float4 -> 4 halves)
    {
        const float* r1base = r1 + ((long)(b * 48) + it * 16) * 300;
        const float* r2base = r2 + ((long)(b * 48) + jt * 16) * 300;
        for (int u = tid; u < 1200; u += 256) {
            int row = u / 75;
            int e4 = (u - row * 75) * 4;
            float4 v1 = *reinterpret_cast<const float4*>(r1base + row * 300 + e4);
            float4 v2 = *reinterpret_cast<const float4*>(r2base + row * 300 + e4);
            _Float16* d1 = r1h + row * RS + e4;
            _Float16* d2 = r2h + row * RS + e4;
            d1[0] = (_Float16)v1.x; d1[1] = (_Float16)v1.y; d1[2] = (_Float16)v1.z; d1[3] = (_Float16)v1.w;
            d2[0] = (_Float16)v2.x; d2[1] = (_Float16)v2.y; d2[2] = (_Float16)v2.z; d2[3] = (_Float16)v2.w;
        }
        for (int u = tid; u < 2 * 16 * (RS - 300); u += 256) {
            int half = u / (16 * (RS - 300));
            int rest = u - half * 16 * (RS - 300);
            int row = rest / (RS - 300);
            int e = 300 + rest - row * (RS - 300);
            (half ? r2h : r1h)[row * RS + e] = (_Float16)0.f;
        }
    }
    __syncthreads();

    int w    = tid >> 6;
    int lane = tid & 63;
    int q    = lane >> 4;
    int jcol = lane & 15;

    float4v acc[4][4];
#pragma unroll
    for (int mt = 0; mt < 4; ++mt)
#pragma unroll
        for (int nt = 0; nt < 4; ++nt) acc[mt][nt] = (float4v){0.f, 0.f, 0.f, 0.f};

    const _Float16* bbase = Bp2 + (long)(nc * 19) * 2048;   // chunk stride 4*64*8=2048
    half8 b0 = *reinterpret_cast<const half8*>(bbase + lane * 8);
    half8 b1 = *reinterpret_cast<const half8*>(bbase + 512 + lane * 8);
    half8 b2 = *reinterpret_cast<const half8*>(bbase + 1024 + lane * 8);
    half8 b3 = *reinterpret_cast<const half8*>(bbase + 1536 + lane * 8);

    for (int kc = 0; kc < 19; ++kc) {
        half8 n0, n1, n2, n3;
        if (kc < 18) {
            const _Float16* nb = bbase + (long)(kc + 1) * 2048;
            n0 = *reinterpret_cast<const half8*>(nb + lane * 8);
            n1 = *reinterpret_cast<const half8*>(nb + 512 + lane * 8);
            n2 = *reinterpret_cast<const half8*>(nb + 1024 + lane * 8);
            n3 = *reinterpret_cast<const half8*>(nb + 1536 + lane * 8);
        } else { n0 = b0; n1 = b1; n2 = b2; n3 = b3; }

        int k0q = kc * 32 + q * 8;
        int koff = (k0q < 304) ? k0q : (k0q - 304);
        const half8 rv2 = *reinterpret_cast<const half8*>(r2h + jcol * RS + koff);
        half8 afr[4];
#pragma unroll
        for (int mt = 0; mt < 4; ++mt) {
            const half8 rv1 = *reinterpret_cast<const half8*>(r1h + (w * 4 + mt) * RS + koff);
            if (k0q < 304) {
                half8 dsub = rv1 - rv2;
                short8 s;
                __builtin_memcpy(&s, &dsub, 16);
                s &= (short)0x7FFF;
                __builtin_memcpy(&afr[mt], &s, 16);
            } else {
                afr[mt] = rv1 * rv2;
            }
        }
#pragma unroll
        for (int mt = 0; mt < 4; ++mt) {
            acc[mt][0] = __builtin_amdgcn_mfma_f32_16x16x32_f16(afr[mt], b0, acc[mt][0], 0, 0, 0);
            acc[mt][1] = __builtin_amdgcn_mfma_f32_16x16x32_f16(afr[mt], b1, acc[mt][1], 0, 0, 0);
            acc[mt][2] = __builtin_amdgcn_mfma_f32_16x16x32_f16(afr[mt], b2, acc[mt][2], 0, 0, 0);
            acc[mt][3] = __builtin_amdgcn_mfma_f32_16x16x32_f16(afr[mt], b3, acc[mt][3], 0, 0, 0);
        }
        b0 = n0; b1 = n1; b2 = n2; b3 = n3;
    }

    // ---- s1: max over valid j (registers + shfl, no LDS) ----
#pragma unroll
    for (int mt = 0; mt < 4; ++mt) {
        int i_l = w * 4 + mt;
#pragma unroll
        for (int nt = 0; nt < 4; ++nt) {
            float mx = NEGP;
#pragma unroll
            for (int r = 0; r < 4; ++r) {
                int j = q * 4 + r;
                if (jt * 16 + j < q2l) mx = fmaxf(mx, acc[mt][nt][r]);
            }
            mx = fmaxf(mx, __shfl_xor(mx, 16));
            mx = fmaxf(mx, __shfl_xor(mx, 32));
            int f = nc * 64 + nt * 16 + jcol;
            if (q == 0 && f < 300) s1p[base1 + i_l * 300 + f] = mx;
        }
    }

    // ---- s2: max over valid i, cross-wave via LDS (red aliases r tiles) ----
    __syncthreads();   // all waves done reading r1h/r2h
#pragma unroll
    for (int nt = 0; nt < 4; ++nt) {
#pragma unroll
        for (int r = 0; r < 4; ++r) {
            float mx = NEGP;
#pragma unroll
            for (int mt = 0; mt < 4; ++mt) {
                int i = it * 16 + w * 4 + mt;
                if (i < q1l) mx = fmaxf(mx, acc[mt][nt][r]);
            }
            red[((w * 16) + q * 4 + r) * 68 + nt * 16 + jcol] = mx;
        }
    }
    __syncthreads();
    for (int vv = tid; vv < 1024; vv += 256) {
        int j = vv >> 6;
        int fcol = vv & 63;
        float mx = red[j * 68 + fcol];
        mx = fmaxf(mx, red[(16 + j) * 68 + fcol]);
        mx = fmaxf(mx, red[(32 + j) * 68 + fcol]);
        mx = fmaxf(mx, red[(48 + j) * 68 + fcol]);
        int f = nc * 64 + fcol;
        if (f < 300) s2p[base2 + (long)j * 300 + f] = mx;
    }
}

// K3: s = tanh(bias + max over 3 tile-partials)
__global__ void k3_combine(const float* __restrict__ s1p, const float* __restrict__ s2p,
                           const float* __restrict__ fc0b,
                           float* __restrict__ s1, float* __restrict__ s2)
{
    int idx = blockIdx.x * 256 + threadIdx.x;
    if (idx >= 64 * 48 * 300) return;
    int b = idx / 14400;
    int lf = idx - b * 14400;
    int f = lf % 300;
    long p = (long)b * 43200 + lf;
    float m1v = fmaxf(fmaxf(s1p[p], s1p[p + 14400]), s1p[p + 28800]);
    float m2v = fmaxf(fmaxf(s2p[p], s2p[p + 14400]), s2p[p + 28800]);
    float bia = fc0b[f];
    s1[idx] = tanhf(m1v + bia);
    s2[idx] = tanhf(m2v + bia);
}

// K4: attention pooling, 256 threads per (side,b), coalesced + shuffle reduce
__global__ __launch_bounds__(256) void k4_pool(
    const float* __restrict__ r1, const float* __restrict__ r2,
    const float* __restrict__ s1, const float* __restrict__ s2,
    const int* __restrict__ q1_len, const int* __restrict__ q2_len,
    const float* __restrict__ att_w, const float* __restrict__ att_b,
    float* __restrict__ h1, float* __restrict__ h2)
{
    int side = blockIdx.x >> 6;
    int b = blockIdx.x & 63;
    const float* r = (side ? r2 : r1) + (long)b * 48 * 300;
    const float* s = (side ? s2 : s1) + (long)b * 48 * 300;
    int len = (side ? q2_len : q1_len)[b];
    float* h = (side ? h2 : h1) + b * 300;
    int tid = threadIdx.x;
    int w = tid >> 6, lane = tid & 63;
    __shared__ float lg[48];
    __shared__ float aL[48];

    // phase 1: logits, wave w handles l = w*12 .. w*12+11
    for (int li = 0; li < 12; ++li) {
        int l = w * 12 + li;
        float acc = 0.f;
        for (int d = lane; d < 600; d += 64) {
            float v = (d < 300) ? r[l * 300 + d] : s[l * 300 + d - 300];
            acc += v * att_w[d];
        }
#pragma unroll
        for (int off = 32; off >= 1; off >>= 1) acc += __shfl_xor(acc, off);
        if (lane == 0) lg[l] = acc + att_b[0];
    }
    __syncthreads();
    // phase 2: softmax (wave 0)
    if (tid < 64) {
        float lo = (lane < 48) ? lg[lane] : NEGP;
        float ml = (lane < len) ? lo : NEGP;
        float mx = ml;
#pragma unroll
        for (int off = 32; off >= 1; off >>= 1) mx = fmaxf(mx, __shfl_xor(mx, off));
        float ex = (lane < len) ? __expf(lo - mx) : 0.f;
        float sm = ex;
#pragma unroll
        for (int off = 32; off >= 1; off >>= 1) sm += __shfl_xor(sm, off);
        if (lane < 48) aL[lane] = ex / sm;
    }
    __syncthreads();
    // phase 3: h[f] = sum_l aL[l] * s[l][f]  (coalesced over f)
    for (int f = tid; f < 300; f += 256) {
        float acc = 0.f;
        for (int l = 0; l < 48; ++l) acc += aL[l] * s[(long)l * 300 + f];
        h[f] = acc;
    }
}

// K5: final MLP, coalesced via transposed fp16 fc1w
__global__ __launch_bounds__(320) void k5_mlp(
    const float* __restrict__ h1, const float* __restrict__ h2,
    const _Float16* __restrict__ fc1wT, const float* __restrict__ fc1b,
    const float* __restrict__ fc2w, const float* __restrict__ fc2b,
    float* __restrict__ out)
{
    int b = blockIdx.x;
    int t = threadIdx.x;
    __shared__ float hc[600];
    __shared__ float jl[304];
    for (int e = t; e < 600; e += 320)
        hc[e] = (e < 300) ? h1[b * 300 + e] : h2[b * 300 + e - 300];
    __syncthreads();
    if (t < 304) {
        float acc = (t < 300) ? fc1b[t] : 0.f;
#pragma unroll 8
        for (int e = 0; e < 600; ++e)
            acc += hc[e] * (float)fc1wT[(long)e * 304 + t];
        jl[t] = tanhf(acc);
    }
    __syncthreads();
    if (t < 128) {
        int o = t >> 6, lane = t & 63;
        float acc = 0.f;
        for (int g = lane; g < 300; g += 64) acc += jl[g] * fc2w[o * 300 + g];
#pragma unroll
        for (int off = 32; off >= 1; off >>= 1) acc += __shfl_xor(acc, off);
        if (lane == 0) out[b * 2 + o] = acc + fc2b[o];
    }
}

extern "C" void kernel_launch(void* const* d_in, const int* in_sizes, int n_in,
                              void* d_out, int out_size, void* d_ws, size_t ws_size,
                              hipStream_t stream)
{
    const int*   q1     = (const int*)d_in[0];
    const int*   q2     = (const int*)d_in[1];
    const int*   q1_len = (const int*)d_in[2];
    const int*   q2_len = (const int*)d_in[3];
    const float* emb    = (const float*)d_in[4];
    const float* conv_w = (const float*)d_in[5];
    const float* conv_b = (const float*)d_in[6];
    const float* fc0_w  = (const float*)d_in[7];
    const float* fc0_b  = (const float*)d_in[8];
    const float* fc1_w  = (const float*)d_in[9];
    const float* fc1_b  = (const float*)d_in[10];
    const float* fc2_w  = (const float*)d_in[11];
    const float* fc2_b  = (const float*)d_in[12];
    const float* att_w  = (const float*)d_in[13];
    const float* att_b  = (const float*)d_in[14];

    float* ws  = (float*)d_ws;
    float* r1  = ws;
    float* r2  = ws + 921600;
    float* s1p = ws + 1843200;
    float* s2p = ws + 4608000;
    float* s1  = ws + 7372800;
    float* s2  = ws + 8294400;
    float* h1  = ws + 9216000;
    float* h2  = ws + 9235200;
    _Float16* X     = (_Float16*)(ws + 1843200);   // pre-k2 alias of s1p region
    _Float16* Bc    = (_Float16*)(ws + 2826240);   // pre-k2 alias of s1p region
    _Float16* Bp2   = (_Float16*)(ws + 9254400);
    _Float16* fc1wT = (_Float16*)(ws + 9351680);
    float* out = (float*)d_out;

    hipLaunchKernelGGL(kp_all, dim3(1287), dim3(256), 0, stream,
                       q1, q2, emb, conv_w, fc0_w, fc1_w, Bp2, Bc, fc1wT, X);
    hipLaunchKernelGGL(kc_conv, dim3(384), dim3(64), 0, stream,
                       X, Bc, conv_b, r1, r2);
    hipLaunchKernelGGL(k2_joint, dim3(45, 64), dim3(256), 0, stream,
                       r1, r2, q1_len, q2_len, Bp2, s1p, s2p);
    hipLaunchKernelGGL(k3_combine, dim3(3600), dim3(256), 0, stream,
                       s1p, s2p, fc0_b, s1, s2);
    hipLaunchKernelGGL(k4_pool, dim3(128), dim3(256), 0, stream,
                       r1, r2, s1, s2, q1_len, q2_len, att_w, att_b, h1, h2);
    hipLaunchKernelGGL(k5_mlp, dim3(64), dim3(320), 0, stream,
                       h1, h2, fc1wT, fc1_b, fc2_w, fc2_b, out);
}